// Round 6
// baseline (174.740 us; speedup 1.0000x reference)
//
#include <hip/hip_runtime.h>

#define TPB 256
#define NBLK_MAIN 2048   // 8 blocks/CU x 256 CU (proven config); main kernel uses NO LDS
#define NCELL (64 * 64 * 64)   // lattice cells; coords are in [0,64)^3
#define PREP_TPB 256
#define NBLK_PREP (NCELL / PREP_TPB)   // 1024, exact cover

__device__ __forceinline__ float fade_f(float t) {
    // 6t^5 - 15t^4 + 10t^3 (Horner, fmaf)
    return t * t * t * fmaf(t, fmaf(t, 6.0f, -15.0f), 10.0f);
}

__device__ __forceinline__ float lerp_f(float a, float b, float t) {
    return fmaf(t, b - a, a);
}

// gi in [0,12) (clean 4-bit nibble).
// grad3 rows: 0..3 = (±1,±1,0), 4..7 = (±1,0,±1), 8..11 = (0,±1,±1)
// c1 = gi<8 ? dx : dy ; c2 = gi<4 ? dy : dz ; signs = gi&1, gi&2.
__device__ __forceinline__ float gdot_n(unsigned gi, float dx, float dy, float dz) {
    float c1 = (gi < 8u) ? dx : dy;
    float c2 = (gi < 4u) ? dy : dz;
    unsigned s1 = gi << 31;                   // bit0 -> sign of c1
    unsigned s2 = (gi << 30) & 0x80000000u;   // bit1 -> sign of c2
    return __uint_as_float(__float_as_uint(c1) ^ s1)
         + __uint_as_float(__float_as_uint(c2) ^ s2);
}

// ---- prep: fold the whole 3-level hash tree into one u32 per lattice cell ----
// tab[(xi<<12)|(yi<<6)|zi] packs the 8 corner gradient indices, 4 bits each:
// nibble k = gi of corner (x+bit2, y+bit1, z+bit0) in order
//   0:aaa 1:aab 2:aba 3:abb 4:baa 5:bab 6:bba 7:bbb
// ~262k cells, 7 dependent LDS lookups each ≈ 1/32 of the old main-kernel hash
// work -> ~2 us once per launch. 1 MB table is L2-resident per XCD.
__global__ __launch_bounds__(PREP_TPB) void perlin_prep(
    const int* __restrict__ perm, unsigned* __restrict__ tab)
{
    __shared__ unsigned P[512];   // perm doubled: P[i] = perm[i & 255], chained
                                  // indices reach 255+63+1 = 319 < 512
    P[threadIdx.x]       = (unsigned)perm[threadIdx.x];
    P[threadIdx.x + 256] = (unsigned)perm[threadIdx.x];
    __syncthreads();

    int cell = blockIdx.x * PREP_TPB + threadIdx.x;   // grid covers NCELL exactly
    int xi = cell >> 12, yi = (cell >> 6) & 63, zi = cell & 63;

    unsigned A  = P[xi]     + (unsigned)yi;   // perm[xi]+yi      (xi+1 <= 64 ok)
    unsigned B  = P[xi + 1] + (unsigned)yi;   // perm[xi+1]+yi
    unsigned aa = P[A]      + (unsigned)zi;   // perm[(perm[xi]+yi)%256]+zi
    unsigned ab = P[A + 1]  + (unsigned)zi;
    unsigned ba = P[B]      + (unsigned)zi;
    unsigned bb = P[B + 1]  + (unsigned)zi;

    unsigned w =  (P[aa]     % 12u)
               | ((P[aa + 1] % 12u) << 4)
               | ((P[ab]     % 12u) << 8)
               | ((P[ab + 1] % 12u) << 12)
               | ((P[ba]     % 12u) << 16)
               | ((P[ba + 1] % 12u) << 20)
               | ((P[bb]     % 12u) << 24)
               | ((P[bb + 1] % 12u) << 28);
    tab[cell] = w;
}

// ---- main: one depth-1 L2 load per element replaces the 3-level LDS chain ----
// r3-r5 post-mortem: kernel was latency-bound on the dependent LDS walk and the
// backend scheduler defeated every source-level pipelining attempt (VGPR pinned
// at 28 across three restructures). Structural fix: no LDS, no chain.
__device__ __forceinline__ float perlin_cell(float X, float Y, float Z,
                                             const unsigned* __restrict__ tab) {
    // coords in [0,64): floor == trunc
    int xi = (int)X, yi = (int)Y, zi = (int)Z;
    float xf = X - (float)xi, yf = Y - (float)yi, zf = Z - (float)zi;
    unsigned w = tab[(xi << 12) | (yi << 6) | zi];   // all 8 corner gi's
    float u = fade_f(xf), v = fade_f(yf), t = fade_f(zf);
    float xm = xf - 1.0f, ym = yf - 1.0f, zm = zf - 1.0f;

    float g_aaa = gdot_n( w         & 15u, xf, yf, zf);
    float g_aab = gdot_n((w >> 4)   & 15u, xf, yf, zm);
    float g_aba = gdot_n((w >> 8)   & 15u, xf, ym, zf);
    float g_abb = gdot_n((w >> 12)  & 15u, xf, ym, zm);
    float g_baa = gdot_n((w >> 16)  & 15u, xm, yf, zf);
    float g_bab = gdot_n((w >> 20)  & 15u, xm, yf, zm);
    float g_bba = gdot_n((w >> 24)  & 15u, xm, ym, zf);
    float g_bbb = gdot_n( w >> 28       , xm, ym, zm);

    float l1 = lerp_f(g_aaa, g_baa, u);
    float l2 = lerp_f(g_aba, g_bba, u);
    float l3 = lerp_f(g_aab, g_bab, u);
    float l4 = lerp_f(g_abb, g_bbb, u);
    float m1 = lerp_f(l1, l2, v);
    float m2 = lerp_f(l3, l4, v);
    return lerp_f(m1, m2, t);
}

__global__ __launch_bounds__(TPB, 8) void perlin_main(
    const float* __restrict__ xg, const float* __restrict__ yg,
    const float* __restrict__ zg, const unsigned* __restrict__ tab,
    float* __restrict__ out, int nquads)
{
    const float4* x4 = (const float4*)xg;
    const float4* y4 = (const float4*)yg;
    const float4* z4 = (const float4*)zg;
    float4* o4 = (float4*)out;

    const int stride = gridDim.x * TPB;
    for (int q = blockIdx.x * TPB + threadIdx.x; q < nquads; q += stride) {
        float4 xv = x4[q], yv = y4[q], zv = z4[q];
        float4 res;
        res.x = perlin_cell(xv.x, yv.x, zv.x, tab);
        res.y = perlin_cell(xv.y, yv.y, zv.y, tab);
        res.z = perlin_cell(xv.z, yv.z, zv.z, tab);
        res.w = perlin_cell(xv.w, yv.w, zv.w, tab);
        o4[q] = res;
    }
}

extern "C" void kernel_launch(void* const* d_in, const int* in_sizes, int n_in,
                              void* d_out, int out_size, void* d_ws, size_t ws_size,
                              hipStream_t stream) {
    const float* x   = (const float*)d_in[0];
    const float* y   = (const float*)d_in[1];
    const float* z   = (const float*)d_in[2];
    const int* perm  = (const int*)d_in[3];
    // d_in[4] (grad3) unused: gradients derived arithmetically from the index
    float* out = (float*)d_out;
    unsigned* tab = (unsigned*)d_ws;   // 1 MB cell table in workspace

    int nquads = out_size >> 2;  // 32*512*512 divisible by 4
    // Stream-ordered: prep -> main, no host sync (graph-capture safe). Prep
    // reruns every launch, so workspace re-poisoning between iterations is fine.
    perlin_prep<<<NBLK_PREP, PREP_TPB, 0, stream>>>(perm, tab);
    perlin_main<<<NBLK_MAIN, TPB, 0, stream>>>(x, y, z, tab, out, nquads);
}

// Round 7
// 143.034 us; speedup vs baseline: 1.2217x; 1.2217x over previous
//
#include <hip/hip_runtime.h>

#define TPB 256
#define NBLK (7 * 256)   // 7 blocks/CU x 256 CU; LDS 22528 B/block -> 7 blocks fit 157.7 KB/CU
#define LREPL 4          // leaf-pair table replication (copy = tid & 3)

__device__ __forceinline__ float fade_f(float t) {
    // 6t^5 - 15t^4 + 10t^3 (Horner, fmaf)
    return t * t * t * fmaf(t, fmaf(t, 6.0f, -15.0f), 10.0f);
}

__device__ __forceinline__ float lerp_f(float a, float b, float t) {
    return fmaf(t, b - a, a);
}

// gi in [0,12) clean.
// grad3 rows: 0..3 = (±1,±1,0), 4..7 = (±1,0,±1), 8..11 = (0,±1,±1)
// c1 = gi<8 ? dx : dy ; c2 = gi<4 ? dy : dz ; signs = gi&1, gi&2.
__device__ __forceinline__ float gdot_n(unsigned gi, float dx, float dy, float dz) {
    float c1 = (gi < 8u) ? dx : dy;
    float c2 = (gi < 4u) ? dy : dz;
    unsigned s1 = gi << 31;                   // bit0 -> sign of c1
    unsigned s2 = (gi << 30) & 0x80000000u;   // bit1 -> sign of c2
    return __uint_as_float(__float_as_uint(c1) ^ s1)
         + __uint_as_float(__float_as_uint(c2) ^ s2);
}

// r6 lesson (counter-proven): divergent GLOBAL gather = ~1 line/cyc at TA; LDS is
// the only gather engine. r3-r5 lesson: the 3-level dependent LDS chain is the
// wall and source-level scheduling can't hide it. This version cuts the chain to
// 2 LDS levels by precomputing the (xi,yi) half of the hash per block:
//   T2[xi*64+yi] = aa | ab<<8 | ba<<16 | bb<<24   (each = perm[perm[x*]+yi] chain mid-value)
//   Lf[i]        = gi(i) | gi(i+1)<<16, i in [0,320)  (leaf pair, no wrap mask needed)
// Per element: 1 b32 (T2) -> 4 independent b32 (Lf). 5 LDS instrs, 2 levels.
__device__ __forceinline__ float perlin_e(float X, float Y, float Z,
                                          const unsigned* __restrict__ T2,
                                          const char* __restrict__ Tl) {
    // coords in [0,64): floor == trunc
    int xi = (int)X, yi = (int)Y, zi = (int)Z;
    float xf = X - (float)xi, yf = Y - (float)yi, zf = Z - (float)zi;
    unsigned w2 = T2[(xi << 6) | yi];          // level 1: all four mid values
    unsigned zi4 = (unsigned)zi << 4;          // leaf entry stride = LREPL*4 = 16 B
    float u = fade_f(xf), v = fade_f(yf), w = fade_f(zf);
    float xm = xf - 1.0f, ym = yf - 1.0f, zm = zf - 1.0f;

    // level 2: four independent leaf-pair reads; (mid+zi) <= 318 < 320, no mask
    unsigned qaa = *(const unsigned*)(Tl + ((( w2        & 255u) << 4) + zi4));
    unsigned qab = *(const unsigned*)(Tl + ((((w2 >> 8)  & 255u) << 4) + zi4));
    unsigned qba = *(const unsigned*)(Tl + ((((w2 >> 16) & 255u) << 4) + zi4));
    unsigned qbb = *(const unsigned*)(Tl + ((( w2 >> 24        ) << 4) + zi4));

    float g_aaa = gdot_n(qaa & 15u,  xf, yf, zf);   // lo16 = gi(z), hi16 = gi(z+1), both clean
    float g_aab = gdot_n(qaa >> 16,  xf, yf, zm);
    float g_aba = gdot_n(qab & 15u,  xf, ym, zf);
    float g_abb = gdot_n(qab >> 16,  xf, ym, zm);
    float g_baa = gdot_n(qba & 15u,  xm, yf, zf);
    float g_bab = gdot_n(qba >> 16,  xm, yf, zm);
    float g_bba = gdot_n(qbb & 15u,  xm, ym, zf);
    float g_bbb = gdot_n(qbb >> 16,  xm, ym, zm);

    float l1 = lerp_f(g_aaa, g_baa, u);
    float l2 = lerp_f(g_aba, g_bba, u);
    float l3 = lerp_f(g_aab, g_bab, u);
    float l4 = lerp_f(g_abb, g_bbb, u);
    float m1 = lerp_f(l1, l2, v);
    float m2 = lerp_f(l3, l4, v);
    return lerp_f(m1, m2, w);
}

__global__ __launch_bounds__(TPB, 7) void perlin_kernel(
    const float* __restrict__ xg, const float* __restrict__ yg,
    const float* __restrict__ zg, const int* __restrict__ perm,
    float* __restrict__ out, int nquads)
{
    __shared__ unsigned       T2[64 * 64];       // 16 KB: packed (aa,ab,ba,bb) per (xi,yi)
    __shared__ unsigned       Lf[320 * LREPL];   // 5 KB: leaf pairs, 4 copies
    __shared__ unsigned short P[512];            // 1 KB: perm doubled (chain idx <= 319)

    for (int s = threadIdx.x; s < 512; s += TPB)
        P[s] = (unsigned short)perm[s & 255];
    __syncthreads();

    // build 2D mid table: 16 entries/thread, short dependent chains, once per block
    for (int c = threadIdx.x; c < 64 * 64; c += TPB) {
        unsigned xi = c >> 6, yi = c & 63u;
        unsigned A = (unsigned)P[xi] + yi;       // <= 318
        unsigned B = (unsigned)P[xi + 1] + yi;   // xi+1 <= 64
        unsigned aa = P[A], ab = P[A + 1];       // A+1 <= 319 < 512
        unsigned ba = P[B], bb = P[B + 1];
        T2[c] = aa | (ab << 8) | (ba << 16) | (bb << 24);
    }
    // build leaf pair table: Lf[i*4+copy] = gi(i) | gi(i+1)<<16
    for (int s = threadIdx.x; s < 320 * LREPL; s += TPB) {
        unsigned i = (unsigned)s >> 2;           // entry index, all copies identical
        Lf[s] = ((unsigned)P[i] % 12u) | (((unsigned)P[i + 1] % 12u) << 16);
    }
    __syncthreads();

    const char* Tl = (const char*)Lf + ((threadIdx.x & (LREPL - 1)) << 2);

    const float4* x4 = (const float4*)xg;
    const float4* y4 = (const float4*)yg;
    const float4* z4 = (const float4*)zg;
    float4* o4 = (float4*)out;

    const int stride = gridDim.x * TPB;
    for (int q = blockIdx.x * TPB + threadIdx.x; q < nquads; q += stride) {
        float4 xv = x4[q], yv = y4[q], zv = z4[q];
        float4 res;
        res.x = perlin_e(xv.x, yv.x, zv.x, T2, Tl);
        res.y = perlin_e(xv.y, yv.y, zv.y, T2, Tl);
        res.z = perlin_e(xv.z, yv.z, zv.z, T2, Tl);
        res.w = perlin_e(xv.w, yv.w, zv.w, T2, Tl);
        o4[q] = res;
    }
}

extern "C" void kernel_launch(void* const* d_in, const int* in_sizes, int n_in,
                              void* d_out, int out_size, void* d_ws, size_t ws_size,
                              hipStream_t stream) {
    const float* x   = (const float*)d_in[0];
    const float* y   = (const float*)d_in[1];
    const float* z   = (const float*)d_in[2];
    const int* perm  = (const int*)d_in[3];
    // d_in[4] (grad3) unused: gradients derived arithmetically from the index
    float* out = (float*)d_out;
    int nquads = out_size >> 2;  // 32*512*512 divisible by 4
    perlin_kernel<<<NBLK, TPB, 0, stream>>>(x, y, z, perm, out, nquads);
}

// Round 8
// 142.564 us; speedup vs baseline: 1.2257x; 1.0033x over previous
//
#include <hip/hip_runtime.h>

#define TPB 256
#define NBLK 1024        // 4 blocks/CU resident (launch_bounds(256,4)); 8 quads/thread exactly
#define LREPL 4          // leaf-pair table replication (copy = tid & 3)

__device__ __forceinline__ float fade_f(float t) {
    return t * t * t * fmaf(t, fmaf(t, 6.0f, -15.0f), 10.0f);
}
__device__ __forceinline__ float lerp_f(float a, float b, float t) {
    return fmaf(t, b - a, a);
}

// gi in [0,12) clean. grad3 rows: 0..3=(±1,±1,0), 4..7=(±1,0,±1), 8..11=(0,±1,±1)
__device__ __forceinline__ float gdot_n(unsigned gi, float dx, float dy, float dz) {
    float c1 = (gi < 8u) ? dx : dy;
    float c2 = (gi < 4u) ? dy : dz;
    unsigned s1 = gi << 31;
    unsigned s2 = (gi << 30) & 0x80000000u;
    return __uint_as_float(__float_as_uint(c1) ^ s1)
         + __uint_as_float(__float_as_uint(c2) ^ s2);
}

// r0-r7 post-mortem: ~45us invariant across -VALU/-LDS/-chain-depth changes;
// VALUBusy back-calc says issue floor is ~26us and the rest is lgkmcnt stall.
// The backend ALWAYS sinks ds_reads next to consumers within a basic block
// (VGPR pinned at 28-36 across 3 restructures). The only scheduler-proof
// structure is a LOOP BACKEDGE: loads issued in iter k, consumed in iter k+1.
// This kernel software-pipelines at loop level with an A/B role swap:
//   half-body: prefetch inputs(n+2) | prolog+T2-issue(n+1) | FINISH(n) | leaf-issue(n+1)
// Leaf(n) latency is covered by prolog(n+1)+FINISH-lead; T2(n+1) by FINISH(n).

// ---- per-quad state (suffix X in {A,B}), element e in 0..3 ----
#define DECL_STATE(X) \
    float    xf##X##0, yf##X##0, zf##X##0, xf##X##1, yf##X##1, zf##X##1,   \
             xf##X##2, yf##X##2, zf##X##2, xf##X##3, yf##X##3, zf##X##3;   \
    unsigned z4##X##0, z4##X##1, z4##X##2, z4##X##3;                       \
    unsigned w2##X##0, w2##X##1, w2##X##2, w2##X##3;                       \
    unsigned aa##X##0, ab##X##0, ba##X##0, bb##X##0,                       \
             aa##X##1, ab##X##1, ba##X##1, bb##X##1,                       \
             aa##X##2, ab##X##2, ba##X##2, bb##X##2,                       \
             aa##X##3, ab##X##3, ba##X##3, bb##X##3;

// prolog + level-1 (T2) issue for one element
#define PRO1(X, e, Xc, Yc, Zc)                                             \
    {   int xi = (int)(Xc), yi = (int)(Yc), zi = (int)(Zc);                \
        xf##X##e = (Xc) - (float)xi;                                       \
        yf##X##e = (Yc) - (float)yi;                                       \
        zf##X##e = (Zc) - (float)zi;                                       \
        z4##X##e = (unsigned)zi << 4;                                      \
        w2##X##e = T2[(xi << 6) | yi];   }

#define PROLOG_T2(X, xv, yv, zv)                                           \
    PRO1(X, 0, (xv).x, (yv).x, (zv).x)                                     \
    PRO1(X, 1, (xv).y, (yv).y, (zv).y)                                     \
    PRO1(X, 2, (xv).z, (yv).z, (zv).z)                                     \
    PRO1(X, 3, (xv).w, (yv).w, (zv).w)

// level-2 (leaf) issue: consumes w2, issues 4 independent reads per element
#define LEAF1(X, e)                                                        \
    aa##X##e = *(const unsigned*)(Tl + ((( w2##X##e        & 255u) << 4) + z4##X##e)); \
    ab##X##e = *(const unsigned*)(Tl + ((((w2##X##e >> 8)  & 255u) << 4) + z4##X##e)); \
    ba##X##e = *(const unsigned*)(Tl + ((((w2##X##e >> 16) & 255u) << 4) + z4##X##e)); \
    bb##X##e = *(const unsigned*)(Tl + ((( w2##X##e >> 24        ) << 4) + z4##X##e));

#define LEAF(X) LEAF1(X, 0) LEAF1(X, 1) LEAF1(X, 2) LEAF1(X, 3)

// finish one element: fades + 8 gdot + 7 lerp (consumes leaf words of X)
#define FIN1(X, e, R)                                                      \
    {   float u = fade_f(xf##X##e), v = fade_f(yf##X##e), w = fade_f(zf##X##e); \
        float xm = xf##X##e - 1.0f, ym = yf##X##e - 1.0f, zm = zf##X##e - 1.0f; \
        float g0 = gdot_n(aa##X##e & 15u, xf##X##e, yf##X##e, zf##X##e);   \
        float g1 = gdot_n(aa##X##e >> 16, xf##X##e, yf##X##e, zm);         \
        float g2 = gdot_n(ab##X##e & 15u, xf##X##e, ym,       zf##X##e);   \
        float g3 = gdot_n(ab##X##e >> 16, xf##X##e, ym,       zm);         \
        float g4 = gdot_n(ba##X##e & 15u, xm,       yf##X##e, zf##X##e);   \
        float g5 = gdot_n(ba##X##e >> 16, xm,       yf##X##e, zm);         \
        float g6 = gdot_n(bb##X##e & 15u, xm,       ym,       zf##X##e);   \
        float g7 = gdot_n(bb##X##e >> 16, xm,       ym,       zm);         \
        float l1 = lerp_f(g0, g4, u), l2 = lerp_f(g2, g6, u);              \
        float l3 = lerp_f(g1, g5, u), l4 = lerp_f(g3, g7, u);              \
        R = lerp_f(lerp_f(l1, l2, v), lerp_f(l3, l4, v), w);   }

#define FINISH(X, qi)                                                      \
    {   float r0, r1, r2, r3;                                              \
        FIN1(X, 0, r0) FIN1(X, 1, r1) FIN1(X, 2, r2) FIN1(X, 3, r3)        \
        o4[qi] = make_float4(r0, r1, r2, r3);   }

__global__ __launch_bounds__(TPB, 4) void perlin_kernel(
    const float* __restrict__ xg, const float* __restrict__ yg,
    const float* __restrict__ zg, const int* __restrict__ perm,
    float* __restrict__ out, int nquads)
{
    // tables identical to r7 (proven: conflicts 2.99M, clean traffic)
    __shared__ unsigned       T2[64 * 64];       // 16 KB: (aa,ab,ba,bb) per (xi,yi)
    __shared__ unsigned       Lf[320 * LREPL];   // 5 KB: gi(i) | gi(i+1)<<16, 4 copies
    __shared__ unsigned short P[512];            // 1 KB: perm doubled

    for (int s = threadIdx.x; s < 512; s += TPB)
        P[s] = (unsigned short)perm[s & 255];
    __syncthreads();

    for (int c = threadIdx.x; c < 64 * 64; c += TPB) {
        unsigned xi = c >> 6, yi = c & 63u;
        unsigned A = (unsigned)P[xi] + yi;
        unsigned B = (unsigned)P[xi + 1] + yi;
        T2[c] = (unsigned)P[A] | ((unsigned)P[A + 1] << 8)
              | ((unsigned)P[B] << 16) | ((unsigned)P[B + 1] << 24);
    }
    for (int s = threadIdx.x; s < 320 * LREPL; s += TPB) {
        unsigned i = (unsigned)s >> 2;
        Lf[s] = ((unsigned)P[i] % 12u) | (((unsigned)P[i + 1] % 12u) << 16);
    }
    __syncthreads();

    const char* Tl = (const char*)Lf + ((threadIdx.x & (LREPL - 1)) << 2);

    const float4* x4 = (const float4*)xg;
    const float4* y4 = (const float4*)yg;
    const float4* z4 = (const float4*)zg;
    float4* o4 = (float4*)out;

    const int S = gridDim.x * TPB;          // 262144; nquads == 8*S exactly
    int q = blockIdx.x * TPB + threadIdx.x; // quad 0 of this thread

    DECL_STATE(A)
    DECL_STATE(B)

    // ---- preamble: inputs for quads 0,1; fully stage quad 0 into A ----
    float4 iax = x4[q],     iay = y4[q],     iaz = z4[q];
    float4 ibx = x4[q + S], iby = y4[q + S], ibz = z4[q + S];
    PROLOG_T2(A, iax, iay, iaz)
    LEAF(A)                                  // one exposed T2 wait, once per thread

    // ---- steady loop: 3 iterations x 2 quads (role swap kills rotate movs) ----
    for (int it = 0; it < 3; ++it) {
        // half 1: finish quad q (A), stage quad q+S (B)
        float4 icx = x4[q + 2 * S], icy = y4[q + 2 * S], icz = z4[q + 2 * S];
        PROLOG_T2(B, ibx, iby, ibz)          // T2(B) in flight...
        FINISH(A, q)                         // ...covered by finishing A (leaf-A waits
                                             //    lgkmcnt(4), T2-B stays outstanding)
        LEAF(B)                              // leaf(B) in flight across the backedge/half
        // half 2: finish quad q+S (B), stage quad q+2S (A)
        q += 2 * S;
        ibx = x4[q + S]; iby = y4[q + S]; ibz = z4[q + S];   // quad 2it+3 <= 7: in bounds
        PROLOG_T2(A, icx, icy, icz)
        FINISH(B, q - S)
        LEAF(A)
    }
    // loop exit: finished quads 0..5, A staged with quad 6 (q == q6), ib* = quad 7
    PROLOG_T2(B, ibx, iby, ibz)
    FINISH(A, q)
    LEAF(B)
    FINISH(B, q + S)
}

extern "C" void kernel_launch(void* const* d_in, const int* in_sizes, int n_in,
                              void* d_out, int out_size, void* d_ws, size_t ws_size,
                              hipStream_t stream) {
    const float* x   = (const float*)d_in[0];
    const float* y   = (const float*)d_in[1];
    const float* z   = (const float*)d_in[2];
    const int* perm  = (const int*)d_in[3];
    // d_in[4] (grad3) unused: gradients derived arithmetically from the index
    float* out = (float*)d_out;
    int nquads = out_size >> 2;  // 2097152 == 8 * 1024 * 256
    perlin_kernel<<<NBLK, TPB, 0, stream>>>(x, y, z, perm, out, nquads);
}